// Round 8
// baseline (577.082 us; speedup 1.0000x reference)
//
#include <hip/hip_runtime.h>
#include <hip/hip_bf16.h>

typedef __bf16 bf16x4 __attribute__((ext_vector_type(4)));
typedef __bf16 bf16x8 __attribute__((ext_vector_type(8)));
typedef float  floatx4 __attribute__((ext_vector_type(4)));

#define AS1 __attribute__((address_space(1)))
#define AS3 __attribute__((address_space(3)))

#define BM2 256
#define BN2 256
#define BK2 64
#define HALF (128 * 64)      // elems per half-tile (128 rows x 64 cols)
#define ABUF (2 * HALF)      // elems per double-buffer slot (2 halves)

#define BARRIER() asm volatile("s_barrier" ::: "memory")

// ---------------------------------------------------------------------------
// Prepass: fp32->bf16 (x) and int32->bf16 (wq). Grid-stride, <=2048 blocks,
// 8 elems/thread. ~65us, near its ~48us roofline; total-minus-dispatch
// overhead is ~180us fixed (proven by round-5 single-dispatch experiment).
// ---------------------------------------------------------------------------
__global__ __launch_bounds__(256)
void cvt_both8(const float* __restrict__ xin, const int* __restrict__ win,
               __bf16* __restrict__ xout, __bf16* __restrict__ wout,
               int nx8, int nw8)
{
    const int stride = gridDim.x * 256;
    const int total  = nx8 + nw8;
    for (int i = blockIdx.x * 256 + threadIdx.x; i < total; i += stride) {
        if (i < nx8) {
            const float4* p = reinterpret_cast<const float4*>(xin) + (size_t)i * 2;
            float4 a = p[0], b = p[1];
            bf16x8 h;
            h[0] = (__bf16)a.x; h[1] = (__bf16)a.y; h[2] = (__bf16)a.z; h[3] = (__bf16)a.w;
            h[4] = (__bf16)b.x; h[5] = (__bf16)b.y; h[6] = (__bf16)b.z; h[7] = (__bf16)b.w;
            reinterpret_cast<bf16x8*>(xout)[i] = h;
        } else {
            int j = i - nx8;
            const int4* p = reinterpret_cast<const int4*>(win) + (size_t)j * 2;
            int4 a = p[0], b = p[1];
            bf16x8 h;
            h[0] = (__bf16)(float)a.x; h[1] = (__bf16)(float)a.y;
            h[2] = (__bf16)(float)a.z; h[3] = (__bf16)(float)a.w;
            h[4] = (__bf16)(float)b.x; h[5] = (__bf16)(float)b.y;
            h[6] = (__bf16)(float)b.z; h[7] = (__bf16)(float)b.w;
            reinterpret_cast<bf16x8*>(wout)[j] = h;
        }
    }
}

// ---------------------------------------------------------------------------
// GEMM v10 — "flow" structure: barriers ONLY at K-tile granularity (2/tile),
// no intra-tile phase barriers. Rationale (round-7 arithmetic): observed
// 4875 cyc/tile == MFMA floor (2064) + LDS service (~2800) exactly — the
// per-phase barrier cadence of v7/v8/v9 serialized the LDS port against the
// matrix pipe. Within a K-tile the read buffer is stable, so no barrier is
// needed between quadrant clusters; ds_reads are software-pipelined one
// cluster ahead (two named A-frag sets, rule #20) and the compiler's
// fine-grained lgkmcnt gates each cluster (m97 note). Staging keeps the
// counted-vmcnt discipline: per tile { body; BARRIER(WAR); stage(kt+2)->
// buf c (8 gload_lds); vmcnt(8) [drains stage(kt+1)]; BARRIER(publish) }.
// vmcnt never 0 in the loop; phantoms land in the dead buffer.
// ---------------------------------------------------------------------------
template<int Q>
__device__ __forceinline__ void mfma16(floatx4 (&acc)[8][4],
                                       const bf16x8 (&af)[2][2],
                                       const bf16x8 (&bfr)[4][2])
{
#pragma unroll
    for (int h = 0; h < 2; ++h)
#pragma unroll
        for (int ii = 0; ii < 2; ++ii)
#pragma unroll
            for (int j = 0; j < 4; ++j)
                acc[2 * Q + ii][j] = __builtin_amdgcn_mfma_f32_16x16x32_bf16(
                    af[ii][h], bfr[j][h], acc[2 * Q + ii][j], 0, 0, 0);
}

// read A fragments for one quadrant from a half-tile base (rows within half)
__device__ __forceinline__ void read_afH(bf16x8 (&dst)[2][2], const __bf16* p,
                                         int rowBase, int lm, int kq, int sw)
{
#pragma unroll
    for (int ii = 0; ii < 2; ++ii)
#pragma unroll
        for (int h = 0; h < 2; ++h)
            dst[ii][h] = *reinterpret_cast<const bf16x8*>(
                &p[(rowBase + ii * 16 + lm) * 64 + ((kq + h * 4) ^ sw) * 8]);
}

// read all 8 B fragments (4 n-frags x 2 k-halves) from a half-tile base
__device__ __forceinline__ void read_bfH(bf16x8 (&dst)[4][2], const __bf16* p,
                                         int wnh, int lm, int kq, int sw)
{
#pragma unroll
    for (int j = 0; j < 4; ++j)
#pragma unroll
        for (int h = 0; h < 2; ++h)
            dst[j][h] = *reinterpret_cast<const bf16x8*>(
                &p[(wnh + j * 16 + lm) * 64 + ((kq + h * 4) ^ sw) * 8]);
}

// one K-tile: 24 ds_reads pipelined one cluster ahead, 64 MFMA, no barriers
__device__ __forceinline__ void tile_body(const __bf16* aHp, const __bf16* bHp,
                                          floatx4 (&acc)[8][4],
                                          int wnh, int lm, int kq, int sw)
{
    bf16x8 bfr[4][2], afA[2][2], afB[2][2];
    read_bfH(bfr, bHp, wnh, lm, kq, sw);
    read_afH(afA, aHp, 0,  lm, kq, sw);
    read_afH(afB, aHp, 32, lm, kq, sw);   // Q1 reads ahead of Q0's cluster
    mfma16<0>(acc, afA, bfr);
    read_afH(afA, aHp, 64, lm, kq, sw);   // Q2 reads under Q1's cluster
    mfma16<1>(acc, afB, bfr);
    read_afH(afB, aHp, 96, lm, kq, sw);   // Q3 reads under Q2's cluster
    mfma16<2>(acc, afA, bfr);
    mfma16<3>(acc, afB, bfr);
}

__global__ __launch_bounds__(512)
void gemm_bf16_bt_flow(const __bf16* __restrict__ A, const __bf16* __restrict__ B,
                       const float* __restrict__ scale, const float* __restrict__ bias,
                       float* __restrict__ Out, int M, int N, int K)
{
    __shared__ __bf16 sA[2 * ABUF];   // 64 KB: [dbuf][half][128r x 64c]
    __shared__ __bf16 sB[2 * ABUF];   // 64 KB

    const int tid  = threadIdx.x;
    const int wave = tid >> 6;
    const int lane = tid & 63;
    const int row0 = blockIdx.y * BM2;
    const int col0 = blockIdx.x * BN2;

    // staging: one gload_lds = 512thr x 16B = 8KB = 64 rows. Half = 2 calls.
    // LDS[row][blk] = G[row][blk ^ (row&7)] (linear dest, pre-swizzled src).
    const int sRow = lane >> 3;
    const int gBlk = (lane & 7) ^ sRow;
    const size_t aBase = (size_t)(row0 + wave * 8 + sRow) * K + gBlk * 8;
    const size_t bBase = (size_t)(col0 + wave * 8 + sRow) * K + gBlk * 8;
    const int dOff = wave * 8 * 64;   // wave-uniform dest offset in a 64-row chunk

#define STG_A(buf, h, sub, kt_) \
    __builtin_amdgcn_global_load_lds( \
        (const AS1 void*)(A + aBase + (size_t)((h) * 128 + (sub) * 64) * K + (size_t)(kt_) * BK2), \
        (AS3 void*)(sA + (buf) * ABUF + (h) * HALF + (sub) * 64 * 64 + dOff), 16, 0, 0)
#define STG_B(buf, h, sub, kt_) \
    __builtin_amdgcn_global_load_lds( \
        (const AS1 void*)(B + bBase + (size_t)((h) * 128 + (sub) * 64) * K + (size_t)(kt_) * BK2), \
        (AS3 void*)(sB + (buf) * ABUF + (h) * HALF + (sub) * 64 * 64 + dOff), 16, 0, 0)
#define STGH_A(buf, h, kt_) do { STG_A(buf, h, 0, kt_); STG_A(buf, h, 1, kt_); } while (0)
#define STGH_B(buf, h, kt_) do { STG_B(buf, h, 0, kt_); STG_B(buf, h, 1, kt_); } while (0)
#define STG_TILE(buf, kt_) do { STGH_B(buf, 0, kt_); STGH_B(buf, 1, kt_); \
                                STGH_A(buf, 0, kt_); STGH_A(buf, 1, kt_); } while (0)

    // fragment geometry: wave -> (wm, wn); each wave touches ONE A-half, ONE B-half
    const int hA  = wave >> 2;            // wm = hA*128
    const int hB  = (wave & 3) >> 1;      // wn = (wave&3)*64
    const int wnh = (wave & 1) * 64;      // row base of wn within its half
    const int lm  = lane & 15;
    const int kq  = lane >> 4;
    const int sw  = lm & 7;

    const __bf16* aH[2] = { sA + hA * HALF, sA + ABUF + hA * HALF };
    const __bf16* bH[2] = { sB + hB * HALF, sB + ABUF + hB * HALF };

    floatx4 acc[8][4];
#pragma unroll
    for (int i = 0; i < 8; ++i)
#pragma unroll
        for (int j = 0; j < 4; ++j)
            acc[i][j] = (floatx4)0.0f;

    const int nt = K / BK2;   // launcher guarantees even, >= 4

    // --- prologue: tile0 -> buf0, tile1 -> buf1 (16 loads). Keep tile1's 8
    // in flight; drain tile0's; publish tile0.
    STG_TILE(0, 0);
    STG_TILE(1, 1);
    asm volatile("s_waitcnt vmcnt(8)" ::: "memory");
    BARRIER();

    for (int kt = 0; kt < nt; ++kt) {
        const int c = kt & 1;
        tile_body(aH[c], bH[c], acc, wnh, lm, kq, sw);
        BARRIER();                                   // WAR: all reads of buf c done
        const int n2 = (kt + 2 < nt) ? kt + 2 : 0;   // phantom lands in dead buf c
        STG_TILE(c, n2);
        asm volatile("s_waitcnt vmcnt(8)" ::: "memory");  // drains stage(kt+1)
        BARRIER();                                   // publish tile kt+1
    }
    asm volatile("s_waitcnt vmcnt(0)" ::: "memory"); // drain phantoms
#undef STG_TILE
#undef STGH_A
#undef STGH_B
#undef STG_A
#undef STG_B

    // --- epilogue: C/D layout col=lane&15, row=(lane>>4)*4+reg (m89-verified)
    const int wm = hA * 128;
    const int wn = (wave & 3) * 64;
#pragma unroll
    for (int j = 0; j < 4; ++j) {
        int n = col0 + wn + j * 16 + lm;
        float sc = scale[n];
        float bi = bias[n];
#pragma unroll
        for (int i = 0; i < 8; ++i) {
#pragma unroll
            for (int r = 0; r < 4; ++r) {
                int m = row0 + wm + i * 16 + kq * 4 + r;
                Out[(size_t)m * N + n] = sc * acc[i][j][r] + bi;
            }
        }
    }
}

// ---------------------------------------------------------------------------
// Last-resort fallback: fused conversion in staging, no workspace needed.
// ---------------------------------------------------------------------------
#define BM 128
#define BN 128

__global__ __launch_bounds__(256)
void fp4linear_gemm(const float* __restrict__ X, const int* __restrict__ W,
                    const float* __restrict__ scale, const float* __restrict__ bias,
                    float* __restrict__ Out, int M, int N, int K)
{
    __shared__ __bf16 sA[BM * 32];
    __shared__ __bf16 sB[BN * 32];

    const int tid  = threadIdx.x;
    const int row0 = blockIdx.y * BM;
    const int col0 = blockIdx.x * BN;
    const int wave = tid >> 6;
    const int lane = tid & 63;
    const int wm = (wave >> 1) * 64;
    const int wn = (wave & 1) * 64;
    const int lm = lane & 15;
    const int kq = lane >> 4;

    floatx4 acc[4][4];
#pragma unroll
    for (int i = 0; i < 4; ++i)
#pragma unroll
        for (int j = 0; j < 4; ++j)
            acc[i][j] = (floatx4)0.0f;

    for (int k0 = 0; k0 < K; k0 += 32) {
        float4 fa[4];
        int4   ib[4];
#pragma unroll
        for (int l = 0; l < 4; ++l) {
            int idx = tid + l * 256;
            int r = idx >> 3, c4 = idx & 7;
            fa[l] = *reinterpret_cast<const float4*>(
                        &X[(size_t)(row0 + r) * K + k0 + c4 * 4]);
        }
#pragma unroll
        for (int l = 0; l < 4; ++l) {
            int idx = tid + l * 256;
            int r = idx >> 3, c4 = idx & 7;
            ib[l] = *reinterpret_cast<const int4*>(
                        &W[(size_t)(col0 + r) * K + k0 + c4 * 4]);
        }
        __syncthreads();
#pragma unroll
        for (int l = 0; l < 4; ++l) {
            int idx = tid + l * 256;
            int r = idx >> 3, c4 = idx & 7;
            bf16x4 h;
            h[0] = (__bf16)fa[l].x; h[1] = (__bf16)fa[l].y;
            h[2] = (__bf16)fa[l].z; h[3] = (__bf16)fa[l].w;
            *reinterpret_cast<bf16x4*>(&sA[r * 32 + c4 * 4]) = h;
        }
#pragma unroll
        for (int l = 0; l < 4; ++l) {
            int idx = tid + l * 256;
            int r = idx >> 3, c4 = idx & 7;
            bf16x4 h;
            h[0] = (__bf16)(float)ib[l].x; h[1] = (__bf16)(float)ib[l].y;
            h[2] = (__bf16)(float)ib[l].z; h[3] = (__bf16)(float)ib[l].w;
            *reinterpret_cast<bf16x4*>(&sB[r * 32 + c4 * 4]) = h;
        }
        __syncthreads();

        bf16x8 af[4], bfr[4];
#pragma unroll
        for (int i = 0; i < 4; ++i)
            af[i] = *reinterpret_cast<const bf16x8*>(
                        &sA[(wm + i * 16 + lm) * 32 + kq * 8]);
#pragma unroll
        for (int j = 0; j < 4; ++j)
            bfr[j] = *reinterpret_cast<const bf16x8*>(
                        &sB[(wn + j * 16 + lm) * 32 + kq * 8]);
#pragma unroll
        for (int i = 0; i < 4; ++i)
#pragma unroll
            for (int j = 0; j < 4; ++j)
                acc[i][j] = __builtin_amdgcn_mfma_f32_16x16x32_bf16(
                                af[i], bfr[j], acc[i][j], 0, 0, 0);
    }

#pragma unroll
    for (int j = 0; j < 4; ++j) {
        int n = col0 + wn + j * 16 + lm;
        float sc = scale[n];
        float bi = bias[n];
#pragma unroll
        for (int i = 0; i < 4; ++i) {
#pragma unroll
            for (int r = 0; r < 4; ++r) {
                int m = row0 + wm + i * 16 + kq * 4 + r;
                Out[(size_t)m * N + n] = sc * acc[i][j][r] + bi;
            }
        }
    }
}

extern "C" void kernel_launch(void* const* d_in, const int* in_sizes, int n_in,
                              void* d_out, int out_size, void* d_ws, size_t ws_size,
                              hipStream_t stream) {
    const float* x     = (const float*)d_in[0];
    const int*   wq    = (const int*)d_in[1];
    const float* scale = (const float*)d_in[2];
    const float* bias  = (const float*)d_in[3];
    float* out = (float*)d_out;

    const int N = in_sizes[2];            // OUT = 4096
    const int K = in_sizes[1] / N;        // IN  = 4096
    const int M = in_sizes[0] / K;        // B*S = 8192

    const size_t xElems = (size_t)M * K;
    const size_t wElems = (size_t)N * K;
    const size_t need   = (xElems + wElems) * sizeof(__bf16);

    const bool cvt_ok = (ws_size >= need) && (xElems % 8 == 0) && (wElems % 8 == 0);
    const int  nt     = K / BK2;
    const bool gemm_ok = (M % BM2 == 0) && (N % BN2 == 0) && (K % BK2 == 0) &&
                         (nt % 2 == 0) && (nt >= 4);

    if (cvt_ok && gemm_ok) {
        __bf16* xb = (__bf16*)d_ws;
        __bf16* wb = xb + xElems;
        int nx8 = (int)(xElems / 8);
        int nw8 = (int)(wElems / 8);
        int total = nx8 + nw8;
        int cvtBlocks = (total + 255) / 256;
        if (cvtBlocks > 2048) cvtBlocks = 2048;
        hipLaunchKernelGGL(cvt_both8, dim3(cvtBlocks), dim3(256), 0, stream,
                           x, wq, xb, wb, nx8, nw8);
        hipLaunchKernelGGL(gemm_bf16_bt_flow, dim3(N / BN2, M / BM2), dim3(512),
                           0, stream, xb, wb, scale, bias, out, M, N, K);
        return;
    }

    hipLaunchKernelGGL(fp4linear_gemm, dim3(N / BN, M / BM), dim3(256), 0, stream,
                       x, wq, scale, bias, out, M, N, K);
}

// Round 9
// 550.656 us; speedup vs baseline: 1.0480x; 1.0480x over previous
//
#include <hip/hip_runtime.h>
#include <hip/hip_bf16.h>

typedef __bf16 bf16x4 __attribute__((ext_vector_type(4)));
typedef __bf16 bf16x8 __attribute__((ext_vector_type(8)));
typedef float  floatx4  __attribute__((ext_vector_type(4)));
typedef float  floatx16 __attribute__((ext_vector_type(16)));

#define AS1 __attribute__((address_space(1)))
#define AS3 __attribute__((address_space(3)))

#define BM2 256
#define BN2 256
#define BK2 64
#define HALF (128 * 64)      // elems per half-tile (128 rows x 64 cols)
#define ABUF (2 * HALF)      // elems per double-buffer slot (2 halves)

#define BARRIER() asm volatile("s_barrier" ::: "memory")

// ---------------------------------------------------------------------------
// Prepass: fp32->bf16 (x) and int32->bf16 (wq). Grid-stride, <=2048 blocks,
// 8 elems/thread. ~65us, near its ~48us roofline; total-minus-dispatch
// overhead is ~180us fixed (round-5 single-dispatch experiment).
// ---------------------------------------------------------------------------
__global__ __launch_bounds__(256)
void cvt_both8(const float* __restrict__ xin, const int* __restrict__ win,
               __bf16* __restrict__ xout, __bf16* __restrict__ wout,
               int nx8, int nw8)
{
    const int stride = gridDim.x * 256;
    const int total  = nx8 + nw8;
    for (int i = blockIdx.x * 256 + threadIdx.x; i < total; i += stride) {
        if (i < nx8) {
            const float4* p = reinterpret_cast<const float4*>(xin) + (size_t)i * 2;
            float4 a = p[0], b = p[1];
            bf16x8 h;
            h[0] = (__bf16)a.x; h[1] = (__bf16)a.y; h[2] = (__bf16)a.z; h[3] = (__bf16)a.w;
            h[4] = (__bf16)b.x; h[5] = (__bf16)b.y; h[6] = (__bf16)b.z; h[7] = (__bf16)b.w;
            reinterpret_cast<bf16x8*>(xout)[i] = h;
        } else {
            int j = i - nx8;
            const int4* p = reinterpret_cast<const int4*>(win) + (size_t)j * 2;
            int4 a = p[0], b = p[1];
            bf16x8 h;
            h[0] = (__bf16)(float)a.x; h[1] = (__bf16)(float)a.y;
            h[2] = (__bf16)(float)a.z; h[3] = (__bf16)(float)a.w;
            h[4] = (__bf16)(float)b.x; h[5] = (__bf16)(float)b.y;
            h[6] = (__bf16)(float)b.z; h[7] = (__bf16)(float)b.w;
            reinterpret_cast<bf16x8*>(wout)[j] = h;
        }
    }
}

// ---------------------------------------------------------------------------
// GEMM v11 — v9's 8-phase skeleton (260us best, tied w/ v7) with two
// register-neutral changes:
//  (1) MFMA shape 16x16x32 -> 32x32x16: 4.03 vs 4.85 cyc/16k-FLOP (m119/m06)
//      => per-tile matrix-pipe floor 2480 -> 2066 cyc. Same LDS traffic,
//      same acc VGPR count (128). Per phase: one 32-row m-tile, 8 MFMAs
//      (2 n-tiles x 4 K-steps of 16).
//      Input frag (by analogy w/ verified 16x16: lane = (m, k-half), 8
//      contiguous k): lane l holds rows l&31, k = (l>>5)*8..+7 of each
//      K=16 step -> 16B-block index ks*2+(l>>5), XOR row&7 store swizzle.
//      C/D (m74/m101-verified): col=lane&31, row=(reg&3)+8*(reg>>2)+4*(l>>5).
//  (2) T1 XCD swizzle: remap linear block id so each XCD owns 2 column
//      panels (2x2MB B = exactly its 4MB L2). B re-reads become L2 hits.
// Stage slots / vmcnt(4)@P4,P8 / liveness: verbatim v9 (re-verified: wave
// halves and row ranges unchanged).
// ---------------------------------------------------------------------------
template<int MT>
__device__ __forceinline__ void mfma8(floatx16 (&acc)[4][2],
                                      const bf16x8 (&af)[4],
                                      const bf16x8 (&bfr)[2][4])
{
#pragma unroll
    for (int ks = 0; ks < 4; ++ks)
#pragma unroll
        for (int nt = 0; nt < 2; ++nt)
            acc[MT][nt] = __builtin_amdgcn_mfma_f32_32x32x16_bf16(
                af[ks], bfr[nt][ks], acc[MT][nt], 0, 0, 0);
}

// A frags for one 32-row m-tile: 4 K-steps, 16B/lane each
__device__ __forceinline__ void read_af32(bf16x8 (&dst)[4], const __bf16* p,
                                          int rowBase, int l31, int kh, int sw)
{
#pragma unroll
    for (int ks = 0; ks < 4; ++ks)
        dst[ks] = *reinterpret_cast<const bf16x8*>(
            &p[(rowBase + l31) * 64 + (((ks * 2 + kh) ^ sw)) * 8]);
}

// all B frags for this wave's 64 cols: 2 n-tiles x 4 K-steps
__device__ __forceinline__ void read_bf32(bf16x8 (&dst)[2][4], const __bf16* p,
                                          int wnh, int l31, int kh, int sw)
{
#pragma unroll
    for (int nt = 0; nt < 2; ++nt)
#pragma unroll
        for (int ks = 0; ks < 4; ++ks)
            dst[nt][ks] = *reinterpret_cast<const bf16x8*>(
                &p[(wnh + nt * 32 + l31) * 64 + (((ks * 2 + kh) ^ sw)) * 8]);
}

__global__ __launch_bounds__(512)
void gemm_bf16_bt_32(const __bf16* __restrict__ A, const __bf16* __restrict__ B,
                     const float* __restrict__ scale, const float* __restrict__ bias,
                     float* __restrict__ Out, int M, int N, int K)
{
    __shared__ __bf16 sA[2 * ABUF];   // 64 KB: [dbuf][half][128r x 64c]
    __shared__ __bf16 sB[2 * ABUF];   // 64 KB

    const int tid  = threadIdx.x;
    const int wave = tid >> 6;
    const int lane = tid & 63;

    // --- T1 XCD swizzle: HW round-robins linear id over 8 XCDs. Remap so
    // each XCD gets a contiguous chunk laid out column-major over tiles ->
    // same-XCD blocks share bx (B panel); 2 panels = 4MB = one XCD L2.
    int bx, by;
    {
        const int lin = blockIdx.y * gridDim.x + blockIdx.x;
        const int nwg = gridDim.x * gridDim.y;
        if ((nwg & 7) == 0) {
            const int chunk = nwg >> 3;
            const int pos = (lin & 7) * chunk + (lin >> 3);
            bx = pos / (int)gridDim.y;
            by = pos % (int)gridDim.y;
        } else { bx = blockIdx.x; by = blockIdx.y; }
    }
    const int row0 = by * BM2;
    const int col0 = bx * BN2;

    // staging: one gload_lds = 512thr x 16B = 8KB = 64 rows. Half = 2 calls.
    // LDS[row][blk] = G[row][blk ^ (row&7)] (linear dest, pre-swizzled src).
    const int sRow = lane >> 3;
    const int gBlk = (lane & 7) ^ sRow;
    const size_t aBase = (size_t)(row0 + wave * 8 + sRow) * K + gBlk * 8;
    const size_t bBase = (size_t)(col0 + wave * 8 + sRow) * K + gBlk * 8;
    const int dOff = wave * 8 * 64;   // wave-uniform dest offset in a 64-row chunk

#define STG_A(buf, h, sub, kt_) \
    __builtin_amdgcn_global_load_lds( \
        (const AS1 void*)(A + aBase + (size_t)((h) * 128 + (sub) * 64) * K + (size_t)(kt_) * BK2), \
        (AS3 void*)(sA + (buf) * ABUF + (h) * HALF + (sub) * 64 * 64 + dOff), 16, 0, 0)
#define STG_B(buf, h, sub, kt_) \
    __builtin_amdgcn_global_load_lds( \
        (const AS1 void*)(B + bBase + (size_t)((h) * 128 + (sub) * 64) * K + (size_t)(kt_) * BK2), \
        (AS3 void*)(sB + (buf) * ABUF + (h) * HALF + (sub) * 64 * 64 + dOff), 16, 0, 0)
#define STGH_A(buf, h, kt_) do { STG_A(buf, h, 0, kt_); STG_A(buf, h, 1, kt_); } while (0)
#define STGH_B(buf, h, kt_) do { STG_B(buf, h, 0, kt_); STG_B(buf, h, 1, kt_); } while (0)

    // fragment geometry: wave -> (wm, wn); each wave touches ONE A-half, ONE B-half
    const int hA  = wave >> 2;            // wm = hA*128
    const int hB  = (wave & 3) >> 1;      // which B half holds this wave's cols
    const int wnh = (wave & 1) * 64;      // col base within the B half
    const int l31 = lane & 31;
    const int kh  = lane >> 5;
    const int sw  = l31 & 7;

    const __bf16* aH[2] = { sA + hA * HALF, sA + ABUF + hA * HALF };
    const __bf16* bH[2] = { sB + hB * HALF, sB + ABUF + hB * HALF };

    floatx16 acc[4][2];
#pragma unroll
    for (int i = 0; i < 4; ++i)
#pragma unroll
        for (int j = 0; j < 2; ++j)
            acc[i][j] = (floatx16)0.0f;

    bf16x8 bfr[2][4];   // current K-tile's B fragments (read once per K-tile)
    bf16x8 af[4];       // current m-tile's A fragments
    const int nt = K / BK2;   // launcher guarantees even, >= 4

    // --- prologue: B(0), A(0) -> buf0; B(1) -> buf1. Drain all but B(1).
    STGH_B(0, 0, 0); STGH_B(0, 1, 0);
    STGH_A(0, 0, 0); STGH_A(0, 1, 0);
    STGH_B(1, 0, 1); STGH_B(1, 1, 1);
    asm volatile("s_waitcnt vmcnt(4)" ::: "memory");
    BARRIER();

#define PH(MT, c, DOB, STAGE, DOVM)                                            \
    do {                                                                       \
        if (DOB) read_bf32(bfr, bH[c], wnh, l31, kh, sw);                      \
        read_af32(af, aH[c], (MT) * 32, l31, kh, sw);                          \
        STAGE;                                                                 \
        BARRIER();                                                             \
        __builtin_amdgcn_sched_barrier(0);                                     \
        __builtin_amdgcn_s_setprio(1);                                         \
        mfma8<MT>(acc, af, bfr);                                               \
        __builtin_amdgcn_s_setprio(0);                                         \
        __builtin_amdgcn_sched_barrier(0);                                     \
        if (DOVM) asm volatile("s_waitcnt vmcnt(4)" ::: "memory");             \
        BARRIER();                                                             \
    } while (0)

    for (int it = 0; it < nt / 2; ++it) {
        const int kt = 2 * it;
        const int e1 = kt + 1;                        // always real
        const int e2 = (kt + 2 < nt) ? kt + 2 : 0;    // phantoms keep FIFO uniform;
        const int e3 = (kt + 3 < nt) ? kt + 3 : 0;    // writes land in dead regions

        PH(0, 0, true,  STGH_A(1, 0, e1), false);     // P1
        PH(1, 0, false, STGH_A(1, 1, e1), false);     // P2
        PH(2, 0, false, STGH_B(0, 0, e2), false);     // P3
        PH(3, 0, false, STGH_B(0, 1, e2), true );     // P4  vmcnt(4)
        PH(0, 1, true,  STGH_A(0, 0, e2), false);     // P5
        PH(1, 1, false, STGH_A(0, 1, e2), false);     // P6
        PH(2, 1, false, STGH_B(1, 0, e3), false);     // P7
        PH(3, 1, false, STGH_B(1, 1, e3), true );     // P8  vmcnt(4)
    }
    asm volatile("s_waitcnt vmcnt(0)" ::: "memory");  // drain phantoms
#undef PH
#undef STGH_A
#undef STGH_B
#undef STG_A
#undef STG_B

    // --- epilogue: 32x32 C/D layout col=lane&31, row=(reg&3)+8*(reg>>2)+4*kh
    const int wm = hA * 128;
    const int wn = (wave & 3) * 64;
#pragma unroll
    for (int ntc = 0; ntc < 2; ++ntc) {
        int n = col0 + wn + ntc * 32 + l31;
        float sc = scale[n];
        float bi = bias[n];
#pragma unroll
        for (int mt = 0; mt < 4; ++mt) {
#pragma unroll
            for (int g = 0; g < 4; ++g) {
#pragma unroll
                for (int r = 0; r < 4; ++r) {
                    int m = row0 + wm + mt * 32 + kh * 4 + g * 8 + r;
                    Out[(size_t)m * N + n] = sc * acc[mt][ntc][g * 4 + r] + bi;
                }
            }
        }
    }
}

// ---------------------------------------------------------------------------
// Last-resort fallback: fused conversion in staging, no workspace needed.
// ---------------------------------------------------------------------------
#define BM 128
#define BN 128

__global__ __launch_bounds__(256)
void fp4linear_gemm(const float* __restrict__ X, const int* __restrict__ W,
                    const float* __restrict__ scale, const float* __restrict__ bias,
                    float* __restrict__ Out, int M, int N, int K)
{
    __shared__ __bf16 sA[BM * 32];
    __shared__ __bf16 sB[BN * 32];

    const int tid  = threadIdx.x;
    const int row0 = blockIdx.y * BM;
    const int col0 = blockIdx.x * BN;
    const int wave = tid >> 6;
    const int lane = tid & 63;
    const int wm = (wave >> 1) * 64;
    const int wn = (wave & 1) * 64;
    const int lm = lane & 15;
    const int kq = lane >> 4;

    floatx4 acc[4][4];
#pragma unroll
    for (int i = 0; i < 4; ++i)
#pragma unroll
        for (int j = 0; j < 4; ++j)
            acc[i][j] = (floatx4)0.0f;

    for (int k0 = 0; k0 < K; k0 += 32) {
        float4 fa[4];
        int4   ib[4];
#pragma unroll
        for (int l = 0; l < 4; ++l) {
            int idx = tid + l * 256;
            int r = idx >> 3, c4 = idx & 7;
            fa[l] = *reinterpret_cast<const float4*>(
                        &X[(size_t)(row0 + r) * K + k0 + c4 * 4]);
        }
#pragma unroll
        for (int l = 0; l < 4; ++l) {
            int idx = tid + l * 256;
            int r = idx >> 3, c4 = idx & 7;
            ib[l] = *reinterpret_cast<const int4*>(
                        &W[(size_t)(col0 + r) * K + k0 + c4 * 4]);
        }
        __syncthreads();
#pragma unroll
        for (int l = 0; l < 4; ++l) {
            int idx = tid + l * 256;
            int r = idx >> 3, c4 = idx & 7;
            bf16x4 h;
            h[0] = (__bf16)fa[l].x; h[1] = (__bf16)fa[l].y;
            h[2] = (__bf16)fa[l].z; h[3] = (__bf16)fa[l].w;
            *reinterpret_cast<bf16x4*>(&sA[r * 32 + c4 * 4]) = h;
        }
#pragma unroll
        for (int l = 0; l < 4; ++l) {
            int idx = tid + l * 256;
            int r = idx >> 3, c4 = idx & 7;
            bf16x4 h;
            h[0] = (__bf16)(float)ib[l].x; h[1] = (__bf16)(float)ib[l].y;
            h[2] = (__bf16)(float)ib[l].z; h[3] = (__bf16)(float)ib[l].w;
            *reinterpret_cast<bf16x4*>(&sB[r * 32 + c4 * 4]) = h;
        }
        __syncthreads();

        bf16x8 af[4], bfr[4];
#pragma unroll
        for (int i = 0; i < 4; ++i)
            af[i] = *reinterpret_cast<const bf16x8*>(
                        &sA[(wm + i * 16 + lm) * 32 + kq * 8]);
#pragma unroll
        for (int j = 0; j < 4; ++j)
            bfr[j] = *reinterpret_cast<const bf16x8*>(
                        &sB[(wn + j * 16 + lm) * 32 + kq * 8]);
#pragma unroll
        for (int i = 0; i < 4; ++i)
#pragma unroll
            for (int j = 0; j < 4; ++j)
                acc[i][j] = __builtin_amdgcn_mfma_f32_16x16x32_bf16(
                                af[i], bfr[j], acc[i][j], 0, 0, 0);
    }

#pragma unroll
    for (int j = 0; j < 4; ++j) {
        int n = col0 + wn + j * 16 + lm;
        float sc = scale[n];
        float bi = bias[n];
#pragma unroll
        for (int i = 0; i < 4; ++i) {
#pragma unroll
            for (int r = 0; r < 4; ++r) {
                int m = row0 + wm + i * 16 + kq * 4 + r;
                Out[(size_t)m * N + n] = sc * acc[i][j][r] + bi;
            }
        }
    }
}

extern "C" void kernel_launch(void* const* d_in, const int* in_sizes, int n_in,
                              void* d_out, int out_size, void* d_ws, size_t ws_size,
                              hipStream_t stream) {
    const float* x     = (const float*)d_in[0];
    const int*   wq    = (const int*)d_in[1];
    const float* scale = (const float*)d_in[2];
    const float* bias  = (const float*)d_in[3];
    float* out = (float*)d_out;

    const int N = in_sizes[2];            // OUT = 4096
    const int K = in_sizes[1] / N;        // IN  = 4096
    const int M = in_sizes[0] / K;        // B*S = 8192

    const size_t xElems = (size_t)M * K;
    const size_t wElems = (size_t)N * K;
    const size_t need   = (xElems + wElems) * sizeof(__bf16);

    const bool cvt_ok = (ws_size >= need) && (xElems % 8 == 0) && (wElems % 8 == 0);
    const int  nt     = K / BK2;
    const bool gemm_ok = (M % BM2 == 0) && (N % BN2 == 0) && (K % BK2 == 0) &&
                         (nt % 2 == 0) && (nt >= 4);

    if (cvt_ok && gemm_ok) {
        __bf16* xb = (__bf16*)d_ws;
        __bf16* wb = xb + xElems;
        int nx8 = (int)(xElems / 8);
        int nw8 = (int)(wElems / 8);
        int total = nx8 + nw8;
        int cvtBlocks = (total + 255) / 256;
        if (cvtBlocks > 2048) cvtBlocks = 2048;
        hipLaunchKernelGGL(cvt_both8, dim3(cvtBlocks), dim3(256), 0, stream,
                           x, wq, xb, wb, nx8, nw8);
        hipLaunchKernelGGL(gemm_bf16_bt_32, dim3(N / BN2, M / BM2), dim3(512),
                           0, stream, xb, wb, scale, bias, out, M, N, K);
        return;
    }

    hipLaunchKernelGGL(fp4linear_gemm, dim3(N / BN, M / BM), dim3(256), 0, stream,
                       x, wq, scale, bias, out, M, N, K);
}

// Round 10
// 509.440 us; speedup vs baseline: 1.1328x; 1.0809x over previous
//
#include <hip/hip_runtime.h>
#include <hip/hip_bf16.h>

typedef __bf16 bf16x4 __attribute__((ext_vector_type(4)));
typedef __bf16 bf16x8 __attribute__((ext_vector_type(8)));
typedef float  floatx4 __attribute__((ext_vector_type(4)));

#define AS1 __attribute__((address_space(1)))
#define AS3 __attribute__((address_space(3)))

#define BM2 256
#define BN2 256
#define BK2 64
#define HALF (128 * 64)      // elems per half-tile (128 rows x 64 cols)
#define ABUF (2 * HALF)      // elems per double-buffer slot (2 halves)

#define BARRIER() asm volatile("s_barrier" ::: "memory")

// ---------------------------------------------------------------------------
// Prepass: fp32->bf16 (x) and int32->bf16 (wq). Grid-stride, <=2048 blocks,
// 8 elems/thread. ~65us (near its ~48us roofline); total-minus-dispatch
// overhead is ~180us fixed (round-5 single-dispatch experiment).
// ---------------------------------------------------------------------------
__global__ __launch_bounds__(256)
void cvt_both8(const float* __restrict__ xin, const int* __restrict__ win,
               __bf16* __restrict__ xout, __bf16* __restrict__ wout,
               int nx8, int nw8)
{
    const int stride = gridDim.x * 256;
    const int total  = nx8 + nw8;
    for (int i = blockIdx.x * 256 + threadIdx.x; i < total; i += stride) {
        if (i < nx8) {
            const float4* p = reinterpret_cast<const float4*>(xin) + (size_t)i * 2;
            float4 a = p[0], b = p[1];
            bf16x8 h;
            h[0] = (__bf16)a.x; h[1] = (__bf16)a.y; h[2] = (__bf16)a.z; h[3] = (__bf16)a.w;
            h[4] = (__bf16)b.x; h[5] = (__bf16)b.y; h[6] = (__bf16)b.z; h[7] = (__bf16)b.w;
            reinterpret_cast<bf16x8*>(xout)[i] = h;
        } else {
            int j = i - nx8;
            const int4* p = reinterpret_cast<const int4*>(win) + (size_t)j * 2;
            int4 a = p[0], b = p[1];
            bf16x8 h;
            h[0] = (__bf16)(float)a.x; h[1] = (__bf16)(float)a.y;
            h[2] = (__bf16)(float)a.z; h[3] = (__bf16)(float)a.w;
            h[4] = (__bf16)(float)b.x; h[5] = (__bf16)(float)b.y;
            h[6] = (__bf16)(float)b.z; h[7] = (__bf16)(float)b.w;
            reinterpret_cast<bf16x8*>(wout)[j] = h;
        }
    }
}

// ---------------------------------------------------------------------------
// GEMM v12 — v9 base (16x16 MFMA, no XCD swizzle; round-9's 32x32 read
// pattern 4-way bank-conflicted [2.5e7] and its swizzle raised FETCH) with
// ONE change: B-read smoothing. v9's P1 issued 12 ds_reads (8 B + 4 A) vs
// 4 in P2-P4. Now:
//   P1-head: bfB (this tile, j=2,3; 4 reads) + af Q0    -> 8 reads
//   P4 post-cluster: bfA (NEXT tile, j=0,1; 4 reads)    -> WAR-safe in the
//      same regs (last consumer was this phase's cluster); latency drains
//      under vmcnt+barrier+next-P1. Zero extra registers.
// Requires B(kt+1) LDS-visible by P4 -> two counted waits per tile:
//   vmcnt(6) at P3-end: outstanding = B(kt+1)(4,kept)+A(kt+1)(4)+B(kt+2)h0(2)
//      = 10 -> drains B(kt+1).
//   vmcnt(4) at P4-end: outstanding = A(kt+1)(4)+B(kt+2)(4) = 8 -> drains
//      A(kt+1), keeps B(kt+2). vmcnt never 0 in the loop.
// Stage map (per tile kt, c=kt&1): P1:A(kt+1)h0->c^1, P2:A(kt+1)h1->c^1,
//   P3:B(kt+2)h0->c, P4:B(kt+2)h1->c. Liveness: B(kt) LDS last read P1-head
//   (bfB), restaged P3 (barrier between); A regions as v9. Phantoms land in
//   dead regions; trailing vmcnt(0) after the loop.
// ---------------------------------------------------------------------------
template<int Q>
__device__ __forceinline__ void mfma16s(floatx4 (&acc)[8][4],
                                        const bf16x8 (&af)[2][2],
                                        const bf16x8 (&bfA)[2][2],
                                        const bf16x8 (&bfB)[2][2])
{
#pragma unroll
    for (int h = 0; h < 2; ++h)
#pragma unroll
        for (int ii = 0; ii < 2; ++ii) {
#pragma unroll
            for (int j = 0; j < 2; ++j)
                acc[2 * Q + ii][j] = __builtin_amdgcn_mfma_f32_16x16x32_bf16(
                    af[ii][h], bfA[j][h], acc[2 * Q + ii][j], 0, 0, 0);
#pragma unroll
            for (int j = 0; j < 2; ++j)
                acc[2 * Q + ii][2 + j] = __builtin_amdgcn_mfma_f32_16x16x32_bf16(
                    af[ii][h], bfB[j][h], acc[2 * Q + ii][2 + j], 0, 0, 0);
        }
}

// A fragments for one quadrant (2 m-frags x 2 k-halves)
__device__ __forceinline__ void read_afH(bf16x8 (&dst)[2][2], const __bf16* p,
                                         int rowBase, int lm, int kq, int sw)
{
#pragma unroll
    for (int ii = 0; ii < 2; ++ii)
#pragma unroll
        for (int h = 0; h < 2; ++h)
            dst[ii][h] = *reinterpret_cast<const bf16x8*>(
                &p[(rowBase + ii * 16 + lm) * BK2 + ((kq + h * 4) ^ sw) * 8]);
}

// 2 B fragments (2 n-frags x 2 k-halves) at a given row base within the half
__device__ __forceinline__ void read_bf2(bf16x8 (&dst)[2][2], const __bf16* p,
                                         int rowBase, int lm, int kq, int sw)
{
#pragma unroll
    for (int j = 0; j < 2; ++j)
#pragma unroll
        for (int h = 0; h < 2; ++h)
            dst[j][h] = *reinterpret_cast<const bf16x8*>(
                &p[(rowBase + j * 16 + lm) * BK2 + ((kq + h * 4) ^ sw) * 8]);
}

__global__ __launch_bounds__(512)
void gemm_bf16_bt_sp(const __bf16* __restrict__ A, const __bf16* __restrict__ B,
                     const float* __restrict__ scale, const float* __restrict__ bias,
                     float* __restrict__ Out, int M, int N, int K)
{
    __shared__ __bf16 sA[2 * ABUF];   // 64 KB: [dbuf][half][128r x 64c]
    __shared__ __bf16 sB[2 * ABUF];   // 64 KB

    const int tid  = threadIdx.x;
    const int wave = tid >> 6;
    const int lane = tid & 63;
    const int row0 = blockIdx.y * BM2;
    const int col0 = blockIdx.x * BN2;

    // staging: one gload_lds = 512thr x 16B = 8KB = 64 rows. Half = 2 calls.
    // LDS[row][blk] = G[row][blk ^ (row&7)] (linear dest, pre-swizzled src).
    const int sRow = lane >> 3;
    const int gBlk = (lane & 7) ^ sRow;
    const size_t aBase = (size_t)(row0 + wave * 8 + sRow) * K + gBlk * 8;
    const size_t bBase = (size_t)(col0 + wave * 8 + sRow) * K + gBlk * 8;
    const int dOff = wave * 8 * 64;   // wave-uniform dest offset in a 64-row chunk

#define STG_A(buf, h, sub, kt_) \
    __builtin_amdgcn_global_load_lds( \
        (const AS1 void*)(A + aBase + (size_t)((h) * 128 + (sub) * 64) * K + (size_t)(kt_) * BK2), \
        (AS3 void*)(sA + (buf) * ABUF + (h) * HALF + (sub) * 64 * 64 + dOff), 16, 0, 0)
#define STG_B(buf, h, sub, kt_) \
    __builtin_amdgcn_global_load_lds( \
        (const AS1 void*)(B + bBase + (size_t)((h) * 128 + (sub) * 64) * K + (size_t)(kt_) * BK2), \
        (AS3 void*)(sB + (buf) * ABUF + (h) * HALF + (sub) * 64 * 64 + dOff), 16, 0, 0)
#define STGH_A(buf, h, kt_) do { STG_A(buf, h, 0, kt_); STG_A(buf, h, 1, kt_); } while (0)
#define STGH_B(buf, h, kt_) do { STG_B(buf, h, 0, kt_); STG_B(buf, h, 1, kt_); } while (0)

    // fragment geometry: wave -> (wm, wn); each wave touches ONE A-half, ONE B-half
    const int hA  = wave >> 2;            // wm = hA*128
    const int hB  = (wave & 3) >> 1;      // which B half holds this wave's cols
    const int wnh = (wave & 1) * 64;      // col base within the B half
    const int lm  = lane & 15;
    const int kq  = lane >> 4;
    const int sw  = lm & 7;

    const __bf16* aH[2] = { sA + hA * HALF, sA + ABUF + hA * HALF };
    const __bf16* bH[2] = { sB + hB * HALF, sB + ABUF + hB * HALF };

    floatx4 acc[8][4];
#pragma unroll
    for (int i = 0; i < 8; ++i)
#pragma unroll
        for (int j = 0; j < 4; ++j)
            acc[i][j] = (floatx4)0.0f;

    bf16x8 bfA[2][2];   // B n-frags j=0,1 (read at P4 of previous tile)
    bf16x8 bfB[2][2];   // B n-frags j=2,3 (read at P1 of this tile)
    bf16x8 af[2][2];    // current quadrant's A fragments
    const int nt = K / BK2;   // launcher guarantees even, >= 4

    // --- prologue: B(0), A(0) -> buf0; B(1) -> buf1. Drain all but B(1).
    STGH_B(0, 0, 0); STGH_B(0, 1, 0);
    STGH_A(0, 0, 0); STGH_A(0, 1, 0);
    STGH_B(1, 0, 1); STGH_B(1, 1, 1);
    asm volatile("s_waitcnt vmcnt(4)" ::: "memory");
    BARRIER();
    read_bf2(bfA, bH[0], wnh, lm, kq, sw);   // tile0 j=0,1

#define PH_HEAD(Q, c)                                                          \
    read_afH(af, aH[c], (Q) * 32, lm, kq, sw)
#define PH_MFMA(Q)                                                             \
    BARRIER();                                                                 \
    __builtin_amdgcn_sched_barrier(0);                                         \
    __builtin_amdgcn_s_setprio(1);                                             \
    mfma16s<Q>(acc, af, bfA, bfB);                                             \
    __builtin_amdgcn_s_setprio(0);                                             \
    __builtin_amdgcn_sched_barrier(0)

#define TILE(c, eA, eB)                                                        \
    /* P1: 4 af + 4 bfB reads */                                               \
    read_bf2(bfB, bH[c], wnh + 32, lm, kq, sw);                                \
    PH_HEAD(0, c);                                                             \
    STGH_A((c) ^ 1, 0, eA);                                                    \
    PH_MFMA(0);                                                                \
    BARRIER();                                                                 \
    /* P2 */                                                                   \
    PH_HEAD(1, c);                                                             \
    STGH_A((c) ^ 1, 1, eA);                                                    \
    PH_MFMA(1);                                                                \
    BARRIER();                                                                 \
    /* P3: vmcnt(6) drains B(kt+1) */                                          \
    PH_HEAD(2, c);                                                             \
    STGH_B((c), 0, eB);                                                        \
    PH_MFMA(2);                                                                \
    asm volatile("s_waitcnt vmcnt(6)" ::: "memory");                           \
    BARRIER();                                                                 \
    /* P4: post-cluster bfA read for next tile; vmcnt(4) drains A(kt+1) */     \
    PH_HEAD(3, c);                                                             \
    STGH_B((c), 1, eB);                                                        \
    PH_MFMA(3);                                                                \
    read_bf2(bfA, bH[(c) ^ 1], wnh, lm, kq, sw);                               \
    asm volatile("s_waitcnt vmcnt(4)" ::: "memory");                           \
    BARRIER();

    for (int it = 0; it < nt / 2; ++it) {
        const int kt = 2 * it;
        const int e1 = kt + 1;                        // always real
        const int e2 = (kt + 2 < nt) ? kt + 2 : 0;    // phantoms keep FIFO uniform;
        const int e3 = (kt + 3 < nt) ? kt + 3 : 0;    // writes land in dead regions
        TILE(0, e1, e2)
        TILE(1, e2, e3)
    }
    asm volatile("s_waitcnt vmcnt(0)" ::: "memory");  // drain phantoms
#undef TILE
#undef PH_MFMA
#undef PH_HEAD
#undef STGH_A
#undef STGH_B
#undef STG_A
#undef STG_B

    // --- epilogue: C/D layout col=lane&15, row=(lane>>4)*4+reg (m89-verified)
    const int wm = hA * 128;
    const int wn = (wave & 3) * 64;
#pragma unroll
    for (int j = 0; j < 4; ++j) {
        int n = col0 + wn + j * 16 + lm;
        float sc = scale[n];
        float bi = bias[n];
#pragma unroll
        for (int i = 0; i < 8; ++i) {
#pragma unroll
            for (int r = 0; r < 4; ++r) {
                int m = row0 + wm + i * 16 + kq * 4 + r;
                Out[(size_t)m * N + n] = sc * acc[i][j][r] + bi;
            }
        }
    }
}

// ---------------------------------------------------------------------------
// Last-resort fallback: fused conversion in staging, no workspace needed.
// ---------------------------------------------------------------------------
#define BM 128
#define BN 128

__global__ __launch_bounds__(256)
void fp4linear_gemm(const float* __restrict__ X, const int* __restrict__ W,
                    const float* __restrict__ scale, const float* __restrict__ bias,
                    float* __restrict__ Out, int M, int N, int K)
{
    __shared__ __bf16 sA[BM * 32];
    __shared__ __bf16 sB[BN * 32];

    const int tid  = threadIdx.x;
    const int row0 = blockIdx.y * BM;
    const int col0 = blockIdx.x * BN;
    const int wave = tid >> 6;
    const int lane = tid & 63;
    const int wm = (wave >> 1) * 64;
    const int wn = (wave & 1) * 64;
    const int lm = lane & 15;
    const int kq = lane >> 4;

    floatx4 acc[4][4];
#pragma unroll
    for (int i = 0; i < 4; ++i)
#pragma unroll
        for (int j = 0; j < 4; ++j)
            acc[i][j] = (floatx4)0.0f;

    for (int k0 = 0; k0 < K; k0 += 32) {
        float4 fa[4];
        int4   ib[4];
#pragma unroll
        for (int l = 0; l < 4; ++l) {
            int idx = tid + l * 256;
            int r = idx >> 3, c4 = idx & 7;
            fa[l] = *reinterpret_cast<const float4*>(
                        &X[(size_t)(row0 + r) * K + k0 + c4 * 4]);
        }
#pragma unroll
        for (int l = 0; l < 4; ++l) {
            int idx = tid + l * 256;
            int r = idx >> 3, c4 = idx & 7;
            ib[l] = *reinterpret_cast<const int4*>(
                        &W[(size_t)(col0 + r) * K + k0 + c4 * 4]);
        }
        __syncthreads();
#pragma unroll
        for (int l = 0; l < 4; ++l) {
            int idx = tid + l * 256;
            int r = idx >> 3, c4 = idx & 7;
            bf16x4 h;
            h[0] = (__bf16)fa[l].x; h[1] = (__bf16)fa[l].y;
            h[2] = (__bf16)fa[l].z; h[3] = (__bf16)fa[l].w;
            *reinterpret_cast<bf16x4*>(&sA[r * 32 + c4 * 4]) = h;
        }
#pragma unroll
        for (int l = 0; l < 4; ++l) {
            int idx = tid + l * 256;
            int r = idx >> 3, c4 = idx & 7;
            bf16x4 h;
            h[0] = (__bf16)(float)ib[l].x; h[1] = (__bf16)(float)ib[l].y;
            h[2] = (__bf16)(float)ib[l].z; h[3] = (__bf16)(float)ib[l].w;
            *reinterpret_cast<bf16x4*>(&sB[r * 32 + c4 * 4]) = h;
        }
        __syncthreads();

        bf16x8 af[4], bfr[4];
#pragma unroll
        for (int i = 0; i < 4; ++i)
            af[i] = *reinterpret_cast<const bf16x8*>(
                        &sA[(wm + i * 16 + lm) * 32 + kq * 8]);
#pragma unroll
        for (int j = 0; j < 4; ++j)
            bfr[j] = *reinterpret_cast<const bf16x8*>(
                        &sB[(wn + j * 16 + lm) * 32 + kq * 8]);
#pragma unroll
        for (int i = 0; i < 4; ++i)
#pragma unroll
            for (int j = 0; j < 4; ++j)
                acc[i][j] = __builtin_amdgcn_mfma_f32_16x16x32_bf16(
                                af[i], bfr[j], acc[i][j], 0, 0, 0);
    }

#pragma unroll
    for (int j = 0; j < 4; ++j) {
        int n = col0 + wn + j * 16 + lm;
        float sc = scale[n];
        float bi = bias[n];
#pragma unroll
        for (int i = 0; i < 4; ++i) {
#pragma unroll
            for (int r = 0; r < 4; ++r) {
                int m = row0 + wm + i * 16 + kq * 4 + r;
                Out[(size_t)m * N + n] = sc * acc[i][j][r] + bi;
            }
        }
    }
}

extern "C" void kernel_launch(void* const* d_in, const int* in_sizes, int n_in,
                              void* d_out, int out_size, void* d_ws, size_t ws_size,
                              hipStream_t stream) {
    const float* x     = (const float*)d_in[0];
    const int*   wq    = (const int*)d_in[1];
    const float* scale = (const float*)d_in[2];
    const float* bias  = (const float*)d_in[3];
    float* out = (float*)d_out;

    const int N = in_sizes[2];            // OUT = 4096
    const int K = in_sizes[1] / N;        // IN  = 4096
    const int M = in_sizes[0] / K;        // B*S = 8192

    const size_t xElems = (size_t)M * K;
    const size_t wElems = (size_t)N * K;
    const size_t need   = (xElems + wElems) * sizeof(__bf16);

    const bool cvt_ok = (ws_size >= need) && (xElems % 8 == 0) && (wElems % 8 == 0);
    const int  nt     = K / BK2;
    const bool gemm_ok = (M % BM2 == 0) && (N % BN2 == 0) && (K % BK2 == 0) &&
                         (nt % 2 == 0) && (nt >= 4);

    if (cvt_ok && gemm_ok) {
        __bf16* xb = (__bf16*)d_ws;
        __bf16* wb = xb + xElems;
        int nx8 = (int)(xElems / 8);
        int nw8 = (int)(wElems / 8);
        int total = nx8 + nw8;
        int cvtBlocks = (total + 255) / 256;
        if (cvtBlocks > 2048) cvtBlocks = 2048;
        hipLaunchKernelGGL(cvt_both8, dim3(cvtBlocks), dim3(256), 0, stream,
                           x, wq, xb, wb, nx8, nw8);
        hipLaunchKernelGGL(gemm_bf16_bt_sp, dim3(N / BN2, M / BM2), dim3(512),
                           0, stream, xb, wb, scale, bias, out, M, N, K);
        return;
    }

    hipLaunchKernelGGL(fp4linear_gemm, dim3(N / BN, M / BM), dim3(256), 0, stream,
                       x, wq, scale, bias, out, M, N, K);
}